// Round 13
// baseline (202.495 us; speedup 1.0000x reference)
//
#include <hip/hip_runtime.h>
#include <stdint.h>

typedef __attribute__((ext_vector_type(8))) __bf16 bf16x8;
typedef __attribute__((ext_vector_type(16))) float f32x16;
typedef __attribute__((ext_vector_type(4))) unsigned int u32x4;
typedef __attribute__((ext_vector_type(2))) float f32x2;
typedef unsigned int u32;
typedef unsigned short u16;

#define THETA 0.7f

__host__ __device__ constexpr float pht_val(int q) {
  return (q == 12) ? (-4.0f + 1e-6f)
       : (q == 7 || q == 11 || q == 13 || q == 17) ? (1.0f + 1e-6f)
       : 1e-6f;
}

__device__ __forceinline__ u16 f2bf(float v) {
  u32 u = __builtin_bit_cast(u32, v);
  return (u16)((u + 0x7fffu + ((u >> 16) & 1u)) >> 16);
}

// ---------------- kernel 1: build K_eff, packed as MFMA A-fragments -------
__global__ __launch_bounds__(256) void k_prep(const float* __restrict__ wgt,
                                              const float* __restrict__ alpha,
                                              u16* __restrict__ apack) {
  int t = blockIdx.x * 256 + threadIdx.x;   // 4096 threads: (o, ci)
  int o = t >> 6, ci = t & 63;
  const float* wp = wgt + ((size_t)(o * 64 + ci)) * 25;
  float wv[25], sumw = 0.f;
#pragma unroll
  for (int p = 0; p < 25; ++p) { wv[p] = wp[p]; sumw += wv[p]; }
  float keff[25];
#pragma unroll
  for (int p = 0; p < 25; ++p) keff[p] = pht_val(p) * wv[p];  // a=0 (identity)
  constexpr int TP[33] = {0,1,2,3,4,6,7,9,12,13,  0,1,2,3,4,  0, 0, 0,
                          0,5,10,15,20,  0,5,6,10,11,12,15,17,20,21};
  constexpr int TQ[33] = {5,6,12,17,23,10,16,22,20,21,  0,5,10,15,20,  5, 0, 5,
                          0,6,7,8,9,  5,6,2,12,8,4,17,9,23,14};
#pragma unroll
  for (int e = 0; e < 33; ++e) keff[TP[e]] += pht_val(TQ[e]) * wv[TQ[e]];

  float al = alpha[0];
  int kc = ci >> 4, oh = o >> 5;
  int lane = ((ci >> 3) & 1) * 32 + (o & 31);   // A-frag: lane=(k/8)*32+m
#pragma unroll
  for (int p = 0; p < 25; ++p) {
    float v = al * (keff[p] * 0.125f);
    if (p == 12) v -= THETA * sumw;             // fold 1x1 branch into center
    size_t idx = ((((size_t)p * 4 + kc) * 2 + oh) * 64 + lane) * 8 + (ci & 7);
    apack[idx] = f2bf(v);
  }
}

// ---------------- kernel 2: FUSED conv, persistent y-loop ring ------------
// Block = (n, px-quarter 32px, y-chunk 16 rows); 128 thr = 2 waves (oh).
// Ring: 12 row-slots x ROWB = 55.5 KB -> 2 blk/CU. Per tile (4 out rows):
// stage 4 NEW rows (T14 issue-early/write-late), R9 SGB compute core, ONE
// lgkm-only raw barrier. BUGFIX vs R12: reload afA=(0,0) at loop top (it
// held stale (4,2) fragments for tiles 1-3 -> absmax 0.707).
#define ROWB 4624
#define NSLOT 12

#define MM(A, B, C) __builtin_amdgcn_mfma_f32_32x32x16_bf16((A), __builtin_bit_cast(bf16x8, (B)), (C), 0, 0, 0)

#define LDBR(S, DX, KC) do {                                                \
    int gx_ = ((((KC) * 2 + lhi) ^ ((l31 + (DX)) & 7)) << 4);               \
    br##S##0 = *(const u32x4*)(rb0 + (DX) * 128 + gx_);                     \
    br##S##1 = *(const u32x4*)(rb1 + (DX) * 128 + gx_);                     \
    br##S##2 = *(const u32x4*)(rb2 + (DX) * 128 + gx_);                     \
    br##S##3 = *(const u32x4*)(rb3 + (DX) * 128 + gx_);                     \
    br##S##4 = *(const u32x4*)(rb4 + (DX) * 128 + gx_);                     \
    br##S##5 = *(const u32x4*)(rb5 + (DX) * 128 + gx_);                     \
    br##S##6 = *(const u32x4*)(rb6 + (DX) * 128 + gx_);                     \
    br##S##7 = *(const u32x4*)(rb7 + (DX) * 128 + gx_);                     \
  } while (0)

#define LDAF(S, DX, KC) do {                                                \
    af##S##0 = apb[(size_t)((0 * 5 + (DX)) * 512 + (KC) * 128)];            \
    af##S##1 = apb[(size_t)((1 * 5 + (DX)) * 512 + (KC) * 128)];            \
    af##S##2 = apb[(size_t)((2 * 5 + (DX)) * 512 + (KC) * 128)];            \
    af##S##3 = apb[(size_t)((3 * 5 + (DX)) * 512 + (KC) * 128)];            \
    af##S##4 = apb[(size_t)((4 * 5 + (DX)) * 512 + (KC) * 128)];            \
  } while (0)

#define BURST(S) do {                                                       \
    bf16x8 A_;                                                              \
    A_ = __builtin_bit_cast(bf16x8, af##S##0);                              \
    a0 = MM(A_, br##S##0, a0); a1 = MM(A_, br##S##1, a1);                   \
    a2 = MM(A_, br##S##2, a2); a3 = MM(A_, br##S##3, a3);                   \
    A_ = __builtin_bit_cast(bf16x8, af##S##1);                              \
    a0 = MM(A_, br##S##1, a0); a1 = MM(A_, br##S##2, a1);                   \
    a2 = MM(A_, br##S##3, a2); a3 = MM(A_, br##S##4, a3);                   \
    A_ = __builtin_bit_cast(bf16x8, af##S##2);                              \
    a0 = MM(A_, br##S##2, a0); a1 = MM(A_, br##S##3, a1);                   \
    a2 = MM(A_, br##S##4, a2); a3 = MM(A_, br##S##5, a3);                   \
    A_ = __builtin_bit_cast(bf16x8, af##S##3);                              \
    a0 = MM(A_, br##S##3, a0); a1 = MM(A_, br##S##4, a1);                   \
    a2 = MM(A_, br##S##5, a2); a3 = MM(A_, br##S##6, a3);                   \
    A_ = __builtin_bit_cast(bf16x8, af##S##4);                              \
    a0 = MM(A_, br##S##4, a0); a1 = MM(A_, br##S##5, a1);                   \
    a2 = MM(A_, br##S##6, a2); a3 = MM(A_, br##S##7, a3);                   \
  } while (0)

#define SGB __builtin_amdgcn_sched_group_barrier
#define SCHED_FULL() do {                                                   \
    SGB(0x020, 5, 0);                                                       \
    SGB(0x100, 2, 0); SGB(0x008, 5, 0);                                     \
    SGB(0x100, 2, 0); SGB(0x008, 5, 0);                                     \
    SGB(0x100, 2, 0); SGB(0x008, 5, 0);                                     \
    SGB(0x100, 2, 0); SGB(0x008, 5, 0);                                     \
  } while (0)

#define ITER(CUR, NXT, DXN, KCN) do {                                       \
    LDBR(NXT, DXN, KCN); LDAF(NXT, DXN, KCN); BURST(CUR); SCHED_FULL();     \
  } while (0)

#define PK(VA, VB) ((u32)f2bf(VA) | ((u32)f2bf(VB) << 16))

// load one staged row (sy = SYE): duty A = 2 granule-slots, duty B halo
#define SLOAD(SYE) do {                                                     \
    int sy_ = (SYE);                                                        \
    bool rok_ = (unsigned)sy_ < 128u;                                       \
    const float* brr_ = xn + (size_t)sy_ * 128;                             \
    if (rok_ && pxAok) {                                                    \
      const float* p0_ = brr_ + (size_t)(8 * g0A) * 16384 + pxA;            \
      const float* p1_ = brr_ + (size_t)(8 * g1A) * 16384 + pxA;            \
      sv0 = *(const f32x2*)(p0_);               sv1 = *(const f32x2*)(p0_ + 16384);     \
      sv2 = *(const f32x2*)(p0_ + 2 * 16384);   sv3 = *(const f32x2*)(p0_ + 3 * 16384); \
      sv4 = *(const f32x2*)(p0_ + 4 * 16384);   sv5 = *(const f32x2*)(p0_ + 5 * 16384); \
      sv6 = *(const f32x2*)(p0_ + 6 * 16384);   sv7 = *(const f32x2*)(p0_ + 7 * 16384); \
      sv8 = *(const f32x2*)(p1_);               sv9 = *(const f32x2*)(p1_ + 16384);     \
      sv10 = *(const f32x2*)(p1_ + 2 * 16384);  sv11 = *(const f32x2*)(p1_ + 3 * 16384);\
      sv12 = *(const f32x2*)(p1_ + 4 * 16384);  sv13 = *(const f32x2*)(p1_ + 5 * 16384);\
      sv14 = *(const f32x2*)(p1_ + 6 * 16384);  sv15 = *(const f32x2*)(p1_ + 7 * 16384);\
    } else {                                                                \
      sv0 = z2; sv1 = z2; sv2 = z2; sv3 = z2; sv4 = z2; sv5 = z2;           \
      sv6 = z2; sv7 = z2; sv8 = z2; sv9 = z2; sv10 = z2; sv11 = z2;         \
      sv12 = z2; sv13 = z2; sv14 = z2; sv15 = z2;                           \
    }                                                                       \
    if (dutyB) {                                                            \
      if (rok_ && pxBok) {                                                  \
        const float* pb_ = brr_ + (size_t)(8 * gB) * 16384 + pxB;           \
        sb0 = *(const f32x2*)(pb_);              sb1 = *(const f32x2*)(pb_ + 16384);     \
        sb2 = *(const f32x2*)(pb_ + 2 * 16384);  sb3 = *(const f32x2*)(pb_ + 3 * 16384); \
        sb4 = *(const f32x2*)(pb_ + 4 * 16384);  sb5 = *(const f32x2*)(pb_ + 5 * 16384); \
        sb6 = *(const f32x2*)(pb_ + 6 * 16384);  sb7 = *(const f32x2*)(pb_ + 7 * 16384); \
      } else {                                                              \
        sb0 = z2; sb1 = z2; sb2 = z2; sb3 = z2;                             \
        sb4 = z2; sb5 = z2; sb6 = z2; sb7 = z2;                             \
      }                                                                     \
    }                                                                       \
  } while (0)

// write the staged row into ring slot WS (cvt + swizzled ds_write_b128)
#define SWRITE(WS) do {                                                     \
    char* wb_ = tile + (size_t)(WS) * ROWB;                                 \
    int c0_ = 2 * cpA;                                                      \
    u32x4 wx_, wy_;                                                         \
    wx_[0] = PK(sv0.x, sv1.x); wx_[1] = PK(sv2.x, sv3.x);                   \
    wx_[2] = PK(sv4.x, sv5.x); wx_[3] = PK(sv6.x, sv7.x);                   \
    wy_[0] = PK(sv0.y, sv1.y); wy_[1] = PK(sv2.y, sv3.y);                   \
    wy_[2] = PK(sv4.y, sv5.y); wy_[3] = PK(sv6.y, sv7.y);                   \
    *(u32x4*)(wb_ + c0_ * 128 + ((g0A ^ (c0_ & 7)) << 4)) = wx_;            \
    *(u32x4*)(wb_ + (c0_ + 1) * 128 + ((g0A ^ ((c0_ + 1) & 7)) << 4)) = wy_;\
    wx_[0] = PK(sv8.x, sv9.x);  wx_[1] = PK(sv10.x, sv11.x);                \
    wx_[2] = PK(sv12.x, sv13.x); wx_[3] = PK(sv14.x, sv15.x);               \
    wy_[0] = PK(sv8.y, sv9.y);  wy_[1] = PK(sv10.y, sv11.y);                \
    wy_[2] = PK(sv12.y, sv13.y); wy_[3] = PK(sv14.y, sv15.y);               \
    *(u32x4*)(wb_ + c0_ * 128 + ((g1A ^ (c0_ & 7)) << 4)) = wx_;            \
    *(u32x4*)(wb_ + (c0_ + 1) * 128 + ((g1A ^ ((c0_ + 1) & 7)) << 4)) = wy_;\
    if (dutyB) {                                                            \
      int cb_ = 2 * cpB;                                                    \
      u32x4 ux_, uy_;                                                       \
      ux_[0] = PK(sb0.x, sb1.x); ux_[1] = PK(sb2.x, sb3.x);                 \
      ux_[2] = PK(sb4.x, sb5.x); ux_[3] = PK(sb6.x, sb7.x);                 \
      uy_[0] = PK(sb0.y, sb1.y); uy_[1] = PK(sb2.y, sb3.y);                 \
      uy_[2] = PK(sb4.y, sb5.y); uy_[3] = PK(sb6.y, sb7.y);                 \
      *(u32x4*)(wb_ + cb_ * 128 + ((gB ^ (cb_ & 7)) << 4)) = ux_;           \
      *(u32x4*)(wb_ + (cb_ + 1) * 128 + ((gB ^ ((cb_ + 1) & 7)) << 4)) = uy_;\
    }                                                                       \
  } while (0)

#define TBAR() do {                                                         \
    asm volatile("s_waitcnt lgkmcnt(0)" ::: "memory");                      \
    __builtin_amdgcn_sched_barrier(0);                                      \
    __builtin_amdgcn_s_barrier();                                           \
    __builtin_amdgcn_sched_barrier(0);                                      \
  } while (0)

__global__ __launch_bounds__(128, 2) void k_conv(const float* __restrict__ x,
                                                 const u32x4* __restrict__ apv,
                                                 float* __restrict__ out) {
  __shared__ char tile[NSLOT * ROWB];         // 55488 B -> 2 blocks/CU
  int bid = blockIdx.x;
  int lg = (bid & 7) * 128 + (bid >> 3);      // XCD swizzle (1024%8==0)
  int pxq = lg & 3, yc = (lg >> 2) & 7, n = lg >> 5;
  int px0 = pxq * 32, yb = yc * 16;
  int tid = threadIdx.x;
  int l = tid & 63, oh = tid >> 6;
  int l31 = l & 31, lhi = l >> 5;

  // stage duties (thread -> one row of each 2-row batch, rrA = oh)
  int rrA = oh;
  int m = tid & 63;
  int cpA = m >> 2;                           // col-pair 0..15
  int g0A = ((m & 3) * 2 + (cpA & 1)) & 7;    // granule pair (bank-dithered)
  int g1A = (g0A + 1) & 7;
  int pxA = px0 + 2 * cpA - 2;
  bool pxAok = pxA >= 0;
  bool dutyB = m < 16;                        // halo col-pairs 16,17
  int cpB = 16 + ((m >> 3) & 1);
  int gB = m & 7;
  int pxB = px0 + 2 * cpB - 2;
  bool pxBok = (pxB + 1) < 128;

  const float* xn = x + (size_t)n * (64 * 16384);
  const f32x2 z2 = {0.f, 0.f};

  f32x2 sv0, sv1, sv2, sv3, sv4, sv5, sv6, sv7;
  f32x2 sv8, sv9, sv10, sv11, sv12, sv13, sv14, sv15;
  f32x2 sb0, sb1, sb2, sb3, sb4, sb5, sb6, sb7;

  // ---- prologue: stage rows r_local 0..7 into slots 0..7 ----
  SLOAD(yb - 2 + 0 + rrA); SWRITE(0 + rrA);
  SLOAD(yb - 2 + 2 + rrA); SWRITE(2 + rrA);
  SLOAD(yb - 2 + 4 + rrA); SWRITE(4 + rrA);
  SLOAD(yb - 2 + 6 + rrA); SWRITE(6 + rrA);

  const u32x4* apb = apv + (size_t)(oh * 64 + l);
  u32x4 brA0, brA1, brA2, brA3, brA4, brA5, brA6, brA7;
  u32x4 brB0, brB1, brB2, brB3, brB4, brB5, brB6, brB7;
  u32x4 afA0, afA1, afA2, afA3, afA4;
  u32x4 afB0, afB1, afB2, afB3, afB4;

  LDAF(A, 0, 0);
  TBAR();

  f32x16 a0 = 0, a1 = 0, a2 = 0, a3 = 0;
  char* tl31 = tile + l31 * 128;
  int b = 0;                                  // ring base = 4*(t%3)

#pragma unroll 1
  for (int t = 0; t < 4; ++t) {
    int s4 = b + 4; if (s4 >= 12) s4 -= 12;
    int s5 = b + 5; if (s5 >= 12) s5 -= 12;
    int s6 = b + 6; if (s6 >= 12) s6 -= 12;
    int s7 = b + 7; if (s7 >= 12) s7 -= 12;
    char* rb0 = tl31 + b * ROWB;
    char* rb1 = tl31 + (b + 1) * ROWB;
    char* rb2 = tl31 + (b + 2) * ROWB;
    char* rb3 = tl31 + (b + 3) * ROWB;
    char* rb4 = tl31 + s4 * ROWB;
    char* rb5 = tl31 + s5 * ROWB;
    char* rb6 = tl31 + s6 * ROWB;
    char* rb7 = tl31 + s7 * ROWB;

    LDBR(A, 0, 0);
    LDAF(A, 0, 0);                            // BUGFIX: afA was stale (4,2)
    ITER(A, B, 0, 1);
    ITER(B, A, 0, 2);
    ITER(A, B, 0, 3);
    ITER(B, A, 1, 0);
    ITER(A, B, 1, 1);
    ITER(B, A, 1, 2);
    if (t < 3) SLOAD(yb + 6 + 4 * t + rrA);   // batch-A row (slots b+8+rrA)
    ITER(A, B, 1, 3);
    ITER(B, A, 2, 0);
    ITER(A, B, 2, 1);
    if (t < 3) {
      int wsA = b + 8 + rrA; if (wsA >= 12) wsA -= 12;
      SWRITE(wsA);
    }
    ITER(B, A, 2, 2);
    ITER(A, B, 2, 3);
    ITER(B, A, 3, 0);
    ITER(A, B, 3, 1);
    ITER(B, A, 3, 2);
    ITER(A, B, 3, 3);
    if (t < 3) SLOAD(yb + 8 + 4 * t + rrA);   // batch-B row (slots b+10+rrA)
    ITER(B, A, 4, 0);
    ITER(A, B, 4, 1);
    ITER(B, A, 4, 2);
    ITER(A, B, 4, 3);
    BURST(B);
    if (t < 3) {
      int wsB = b + 10 + rrA; if (wsB >= 12) wsB -= 12;
      SWRITE(wsB);
    }

    // stores: rows yb+4t .. +3, this wave's 32 o, 32 px
    float* ob = out + ((size_t)(n * 64 + oh * 32) * 128 + (yb + 4 * t)) * 128
                + px0 + l31;
#pragma unroll
    for (int rg = 0; rg < 16; ++rg) {
      int orow = (rg & 3) + 8 * (rg >> 2) + 4 * lhi;
      float* obr = ob + (size_t)orow * 16384;
      obr[0]   = a0[rg];
      obr[128] = a1[rg];
      obr[256] = a2[rg];
      obr[384] = a3[rg];
    }
    a0 = 0; a1 = 0; a2 = 0; a3 = 0;
    TBAR();
    b += 4; if (b >= 12) b -= 12;
  }
}

extern "C" void kernel_launch(void* const* d_in, const int* in_sizes, int n_in,
                              void* d_out, int out_size, void* d_ws, size_t ws_size,
                              hipStream_t stream) {
  const float* x     = (const float*)d_in[0];   // (32,64,128,128) fp32
  const float* wgt   = (const float*)d_in[1];   // (64,64,5,5) fp32
  const float* alpha = (const float*)d_in[2];   // (1,) fp32
  float* out = (float*)d_out;

  u16* apack = (u16*)d_ws;                      // 204800 B

  k_prep<<<16,   256, 0, stream>>>(wgt, alpha, apack);
  k_conv<<<1024, 128, 0, stream>>>(x, (const u32x4*)apack, out);
}

// Round 14
// 122.148 us; speedup vs baseline: 1.6578x; 1.6578x over previous
//
#include <hip/hip_runtime.h>
#include <stdint.h>

typedef __attribute__((ext_vector_type(8))) __bf16 bf16x8;
typedef __attribute__((ext_vector_type(16))) float f32x16;
typedef __attribute__((ext_vector_type(4))) unsigned int u32x4;
typedef __attribute__((ext_vector_type(4))) float f32x4;
typedef __attribute__((ext_vector_type(2))) float f32x2;
typedef unsigned int u32;
typedef unsigned short u16;

#define THETA 0.7f

__host__ __device__ constexpr float pht_val(int q) {
  return (q == 12) ? (-4.0f + 1e-6f)
       : (q == 7 || q == 11 || q == 13 || q == 17) ? (1.0f + 1e-6f)
       : 1e-6f;
}

__device__ __forceinline__ u16 f2bf(float v) {
  u32 u = __builtin_bit_cast(u32, v);
  return (u16)((u + 0x7fffu + ((u >> 16) & 1u)) >> 16);
}

// ---------------- kernel 1: build K_eff, packed as MFMA A-fragments -------
__global__ __launch_bounds__(256) void k_prep(const float* __restrict__ wgt,
                                              const float* __restrict__ alpha,
                                              u16* __restrict__ apack) {
  int t = blockIdx.x * 256 + threadIdx.x;   // 4096 threads: (o, ci)
  int o = t >> 6, ci = t & 63;
  const float* wp = wgt + ((size_t)(o * 64 + ci)) * 25;
  float wv[25], sumw = 0.f;
#pragma unroll
  for (int p = 0; p < 25; ++p) { wv[p] = wp[p]; sumw += wv[p]; }
  float keff[25];
#pragma unroll
  for (int p = 0; p < 25; ++p) keff[p] = pht_val(p) * wv[p];  // a=0 (identity)
  constexpr int TP[33] = {0,1,2,3,4,6,7,9,12,13,  0,1,2,3,4,  0, 0, 0,
                          0,5,10,15,20,  0,5,6,10,11,12,15,17,20,21};
  constexpr int TQ[33] = {5,6,12,17,23,10,16,22,20,21,  0,5,10,15,20,  5, 0, 5,
                          0,6,7,8,9,  5,6,2,12,8,4,17,9,23,14};
#pragma unroll
  for (int e = 0; e < 33; ++e) keff[TP[e]] += pht_val(TQ[e]) * wv[TQ[e]];

  float al = alpha[0];
  int kc = ci >> 4, oh = o >> 5;
  int lane = ((ci >> 3) & 1) * 32 + (o & 31);   // A-frag: lane=(k/8)*32+m
#pragma unroll
  for (int p = 0; p < 25; ++p) {
    float v = al * (keff[p] * 0.125f);
    if (p == 12) v -= THETA * sumw;             // fold 1x1 branch into center
    size_t idx = ((((size_t)p * 4 + kc) * 2 + oh) * 64 + lane) * 8 + (ci & 7);
    apack[idx] = f2bf(v);
  }
}

// ---------------- kernel 2: FUSED conv (cast+stage+MFMA) ------------------
// R10 geometry/compute verbatim (64-px tile, 4 waves (oh,q32), 72 KB,
// 2 blk/CU, 19-ITER SGB core). Stage upgraded per R11's lesson: 72-col
// tile (col c <-> px0+c-4) so main loads are ALIGNED f32x4 (4 px); thread
// = (row-parity, quad, granule); per pass 8 f32x4 loads + 4 bank-balanced
// ds_write_b128 (4x fewer LDS write instrs than R10, zero write conflicts).
#define ROWB 9216   // 72 cols * 128 B

#define MM(A, B, C) __builtin_amdgcn_mfma_f32_32x32x16_bf16((A), __builtin_bit_cast(bf16x8, (B)), (C), 0, 0, 0)

#define LDBR(S, DX, KC) do {                                                \
    const char* pb_ = pcol + (DX) * 128;                                    \
    int gx_ = ((((KC) * 2 + lhi) ^ ((l31 + (DX) + 2) & 7)) << 4);           \
    br##S##0 = *(const u32x4*)(pb_ + 0 * ROWB + gx_);                       \
    br##S##1 = *(const u32x4*)(pb_ + 1 * ROWB + gx_);                       \
    br##S##2 = *(const u32x4*)(pb_ + 2 * ROWB + gx_);                       \
    br##S##3 = *(const u32x4*)(pb_ + 3 * ROWB + gx_);                       \
    br##S##4 = *(const u32x4*)(pb_ + 4 * ROWB + gx_);                       \
    br##S##5 = *(const u32x4*)(pb_ + 5 * ROWB + gx_);                       \
    br##S##6 = *(const u32x4*)(pb_ + 6 * ROWB + gx_);                       \
    br##S##7 = *(const u32x4*)(pb_ + 7 * ROWB + gx_);                       \
  } while (0)

#define LDAF(S, DX, KC) do {                                                \
    af##S##0 = apb[(size_t)((0 * 5 + (DX)) * 512 + (KC) * 128)];            \
    af##S##1 = apb[(size_t)((1 * 5 + (DX)) * 512 + (KC) * 128)];            \
    af##S##2 = apb[(size_t)((2 * 5 + (DX)) * 512 + (KC) * 128)];            \
    af##S##3 = apb[(size_t)((3 * 5 + (DX)) * 512 + (KC) * 128)];            \
    af##S##4 = apb[(size_t)((4 * 5 + (DX)) * 512 + (KC) * 128)];            \
  } while (0)

#define BURST(S) do {                                                       \
    bf16x8 A_;                                                              \
    A_ = __builtin_bit_cast(bf16x8, af##S##0);                              \
    a0 = MM(A_, br##S##0, a0); a1 = MM(A_, br##S##1, a1);                   \
    a2 = MM(A_, br##S##2, a2); a3 = MM(A_, br##S##3, a3);                   \
    A_ = __builtin_bit_cast(bf16x8, af##S##1);                              \
    a0 = MM(A_, br##S##1, a0); a1 = MM(A_, br##S##2, a1);                   \
    a2 = MM(A_, br##S##3, a2); a3 = MM(A_, br##S##4, a3);                   \
    A_ = __builtin_bit_cast(bf16x8, af##S##2);                              \
    a0 = MM(A_, br##S##2, a0); a1 = MM(A_, br##S##3, a1);                   \
    a2 = MM(A_, br##S##4, a2); a3 = MM(A_, br##S##5, a3);                   \
    A_ = __builtin_bit_cast(bf16x8, af##S##3);                              \
    a0 = MM(A_, br##S##3, a0); a1 = MM(A_, br##S##4, a1);                   \
    a2 = MM(A_, br##S##5, a2); a3 = MM(A_, br##S##6, a3);                   \
    A_ = __builtin_bit_cast(bf16x8, af##S##4);                              \
    a0 = MM(A_, br##S##4, a0); a1 = MM(A_, br##S##5, a1);                   \
    a2 = MM(A_, br##S##6, a2); a3 = MM(A_, br##S##7, a3);                   \
  } while (0)

#define SGB __builtin_amdgcn_sched_group_barrier
#define SCHED_FULL() do {                                                   \
    SGB(0x020, 5, 0);              /* 5 VMEM (next af) early */             \
    SGB(0x100, 2, 0); SGB(0x008, 5, 0);                                     \
    SGB(0x100, 2, 0); SGB(0x008, 5, 0);                                     \
    SGB(0x100, 2, 0); SGB(0x008, 5, 0);                                     \
    SGB(0x100, 2, 0); SGB(0x008, 5, 0);                                     \
  } while (0)

#define ITER(CUR, NXT, DXN, KCN) do {                                       \
    LDBR(NXT, DXN, KCN); LDAF(NXT, DXN, KCN); BURST(CUR); SCHED_FULL();     \
  } while (0)

#define PK(VA, VB) ((u32)f2bf(VA) | ((u32)f2bf(VB) << 16))

__global__ __launch_bounds__(256, 2) void k_conv(const float* __restrict__ x,
                                                 const u32x4* __restrict__ apv,
                                                 float* __restrict__ out) {
  __shared__ char tile[8 * ROWB];             // 73728 B -> 2 blocks/CU
  int bid = blockIdx.x;
  int lg = (bid & 7) * 256 + (bid >> 3);      // XCD swizzle (2048%8==0)
  int ph = lg & 1, yt = (lg >> 1) & 31, n = lg >> 6;
  int y0 = yt * 4, px0 = ph * 64;
  int tid = threadIdx.x;
  int l = tid & 63;

  // ---- fused stage: x fp32 -> bf16 -> swizzled tile[r][c][g] ----
  // tile col c holds src px = px0 + c - 4 (cols 2..69 used; 4..67 = main
  // aligned quads, {2,3} left halo, {68,69} right halo).
  {
    const float* xn = x + (size_t)n * (64 * 16384);
    int rp = tid >> 7;                        // row parity
    int q  = (tid >> 3) & 15;                 // px quad
    int g  = tid & 7;                         // granule (8 channels)
    int pxm = px0 + 4 * q;
    int hpx = (q == 0) ? px0 - 2 : px0 + 64;  // halo duty for q<2
    int hc  = (q == 0) ? 2 : 68;
    bool hok = (unsigned)hpx < 127u;          // hpx, hpx+1 both in-image
#pragma unroll
    for (int ps = 0; ps < 4; ++ps) {
      int rr = 2 * ps + rp;
      int sy = y0 + rr - 2;
      bool rowok = (unsigned)sy < 128u;
      char* rowbase = tile + rr * ROWB;
      const float* xr = xn + (size_t)sy * 128;
      f32x4 v0, v1, v2, v3, v4, v5, v6, v7;
      if (rowok) {
        const float* pm = xr + (size_t)(8 * g) * 16384 + pxm;
        v0 = *(const f32x4*)(pm);
        v1 = *(const f32x4*)(pm + 16384);
        v2 = *(const f32x4*)(pm + 2 * 16384);
        v3 = *(const f32x4*)(pm + 3 * 16384);
        v4 = *(const f32x4*)(pm + 4 * 16384);
        v5 = *(const f32x4*)(pm + 5 * 16384);
        v6 = *(const f32x4*)(pm + 6 * 16384);
        v7 = *(const f32x4*)(pm + 7 * 16384);
      } else {
        v0 = 0; v1 = 0; v2 = 0; v3 = 0; v4 = 0; v5 = 0; v6 = 0; v7 = 0;
      }
      int cb = 4 + 4 * q;
      u32x4 w;
      w[0] = PK(v0.x, v1.x); w[1] = PK(v2.x, v3.x);
      w[2] = PK(v4.x, v5.x); w[3] = PK(v6.x, v7.x);
      *(u32x4*)(rowbase + cb * 128 + ((g ^ (cb & 7)) << 4)) = w;
      w[0] = PK(v0.y, v1.y); w[1] = PK(v2.y, v3.y);
      w[2] = PK(v4.y, v5.y); w[3] = PK(v6.y, v7.y);
      *(u32x4*)(rowbase + (cb + 1) * 128 + ((g ^ ((cb + 1) & 7)) << 4)) = w;
      w[0] = PK(v0.z, v1.z); w[1] = PK(v2.z, v3.z);
      w[2] = PK(v4.z, v5.z); w[3] = PK(v6.z, v7.z);
      *(u32x4*)(rowbase + (cb + 2) * 128 + ((g ^ ((cb + 2) & 7)) << 4)) = w;
      w[0] = PK(v0.w, v1.w); w[1] = PK(v2.w, v3.w);
      w[2] = PK(v4.w, v5.w); w[3] = PK(v6.w, v7.w);
      *(u32x4*)(rowbase + (cb + 3) * 128 + ((g ^ ((cb + 3) & 7)) << 4)) = w;
      if (q < 2) {                            // halo cols (2 px)
        f32x2 h0 = {0.f, 0.f}, h1 = {0.f, 0.f}, h2 = {0.f, 0.f}, h3 = {0.f, 0.f};
        f32x2 h4 = {0.f, 0.f}, h5 = {0.f, 0.f}, h6 = {0.f, 0.f}, h7 = {0.f, 0.f};
        if (rowok && hok) {
          const float* phm = xr + (size_t)(8 * g) * 16384 + hpx;
          h0 = *(const f32x2*)(phm);
          h1 = *(const f32x2*)(phm + 16384);
          h2 = *(const f32x2*)(phm + 2 * 16384);
          h3 = *(const f32x2*)(phm + 3 * 16384);
          h4 = *(const f32x2*)(phm + 4 * 16384);
          h5 = *(const f32x2*)(phm + 5 * 16384);
          h6 = *(const f32x2*)(phm + 6 * 16384);
          h7 = *(const f32x2*)(phm + 7 * 16384);
        }
        u32x4 u;
        u[0] = PK(h0.x, h1.x); u[1] = PK(h2.x, h3.x);
        u[2] = PK(h4.x, h5.x); u[3] = PK(h6.x, h7.x);
        *(u32x4*)(rowbase + hc * 128 + ((g ^ (hc & 7)) << 4)) = u;
        u[0] = PK(h0.y, h1.y); u[1] = PK(h2.y, h3.y);
        u[2] = PK(h4.y, h5.y); u[3] = PK(h6.y, h7.y);
        *(u32x4*)(rowbase + (hc + 1) * 128 + ((g ^ ((hc + 1) & 7)) << 4)) = u;
      }
    }
  }

  // ---- compute: wave = (oh = o-half, q32 = px quarter), all 4 rows ----
  int wv = tid >> 6;
  int oh = wv >> 1, q32 = wv & 1;
  int l31 = l & 31, lhi = l >> 5;
  const u32x4* apb = apv + (size_t)(oh * 64 + l);
  const char* pcol = tile + (q32 * 32 + l31 + 2) * 128;

  u32x4 brA0, brA1, brA2, brA3, brA4, brA5, brA6, brA7;
  u32x4 brB0, brB1, brB2, brB3, brB4, brB5, brB6, brB7;
  u32x4 afA0, afA1, afA2, afA3, afA4;
  u32x4 afB0, afB1, afB2, afB3, afB4;

  LDAF(A, 0, 0);                              // iter-0 A-frags hide under
  __syncthreads();                            // the stage drain
  LDBR(A, 0, 0);

  f32x16 a0 = 0, a1 = 0, a2 = 0, a3 = 0;      // acc[row]

  // 20 iterations, (dx outer, kc inner), alternating register sets
  ITER(A, B, 0, 1);
  ITER(B, A, 0, 2);
  ITER(A, B, 0, 3);
  ITER(B, A, 1, 0);
  ITER(A, B, 1, 1);
  ITER(B, A, 1, 2);
  ITER(A, B, 1, 3);
  ITER(B, A, 2, 0);
  ITER(A, B, 2, 1);
  ITER(B, A, 2, 2);
  ITER(A, B, 2, 3);
  ITER(B, A, 3, 0);
  ITER(A, B, 3, 1);
  ITER(B, A, 3, 2);
  ITER(A, B, 3, 3);
  ITER(B, A, 4, 0);
  ITER(A, B, 4, 1);
  ITER(B, A, 4, 2);
  ITER(A, B, 4, 3);
  BURST(B);                                   // last iteration, no prefetch

  // ---- epilogue: C/D layout col=lane&31, row=(rg&3)+8*(rg>>2)+4*(lane>>5)
  float* ob = out + ((size_t)(n * 64 + oh * 32) * 128 + y0) * 128
              + px0 + q32 * 32 + l31;
#pragma unroll
  for (int rg = 0; rg < 16; ++rg) {
    int orow = (rg & 3) + 8 * (rg >> 2) + 4 * lhi;
    float* obr = ob + (size_t)orow * 16384;
    obr[0]   = a0[rg];
    obr[128] = a1[rg];
    obr[256] = a2[rg];
    obr[384] = a3[rg];
  }
}

extern "C" void kernel_launch(void* const* d_in, const int* in_sizes, int n_in,
                              void* d_out, int out_size, void* d_ws, size_t ws_size,
                              hipStream_t stream) {
  const float* x     = (const float*)d_in[0];   // (32,64,128,128) fp32
  const float* wgt   = (const float*)d_in[1];   // (64,64,5,5) fp32
  const float* alpha = (const float*)d_in[2];   // (1,) fp32
  float* out = (float*)d_out;

  u16* apack = (u16*)d_ws;                      // 204800 B

  k_prep<<<16,   256, 0, stream>>>(wgt, alpha, apack);
  k_conv<<<2048, 256, 0, stream>>>(x, (const u32x4*)apack, out);
}

// Round 15
// 116.197 us; speedup vs baseline: 1.7427x; 1.0512x over previous
//
#include <hip/hip_runtime.h>
#include <stdint.h>

typedef __attribute__((ext_vector_type(8))) __bf16 bf16x8;
typedef __attribute__((ext_vector_type(16))) float f32x16;
typedef __attribute__((ext_vector_type(4))) unsigned int u32x4;
typedef __attribute__((ext_vector_type(4))) float f32x4;
typedef __attribute__((ext_vector_type(2))) float f32x2;
typedef unsigned int u32;
typedef unsigned short u16;

#define THETA 0.7f

__host__ __device__ constexpr float pht_val(int q) {
  return (q == 12) ? (-4.0f + 1e-6f)
       : (q == 7 || q == 11 || q == 13 || q == 17) ? (1.0f + 1e-6f)
       : 1e-6f;
}

__device__ __forceinline__ u16 f2bf(float v) {
  u32 u = __builtin_bit_cast(u32, v);
  return (u16)((u + 0x7fffu + ((u >> 16) & 1u)) >> 16);
}

// ---------------- kernel 1: build K_eff, packed as MFMA A-fragments -------
__global__ __launch_bounds__(256) void k_prep(const float* __restrict__ wgt,
                                              const float* __restrict__ alpha,
                                              u16* __restrict__ apack) {
  int t = blockIdx.x * 256 + threadIdx.x;   // 4096 threads: (o, ci)
  int o = t >> 6, ci = t & 63;
  const float* wp = wgt + ((size_t)(o * 64 + ci)) * 25;
  float wv[25], sumw = 0.f;
#pragma unroll
  for (int p = 0; p < 25; ++p) { wv[p] = wp[p]; sumw += wv[p]; }
  float keff[25];
#pragma unroll
  for (int p = 0; p < 25; ++p) keff[p] = pht_val(p) * wv[p];  // a=0 (identity)
  constexpr int TP[33] = {0,1,2,3,4,6,7,9,12,13,  0,1,2,3,4,  0, 0, 0,
                          0,5,10,15,20,  0,5,6,10,11,12,15,17,20,21};
  constexpr int TQ[33] = {5,6,12,17,23,10,16,22,20,21,  0,5,10,15,20,  5, 0, 5,
                          0,6,7,8,9,  5,6,2,12,8,4,17,9,23,14};
#pragma unroll
  for (int e = 0; e < 33; ++e) keff[TP[e]] += pht_val(TQ[e]) * wv[TQ[e]];

  float al = alpha[0];
  int kc = ci >> 4, oh = o >> 5;
  int lane = ((ci >> 3) & 1) * 32 + (o & 31);   // A-frag: lane=(k/8)*32+m
#pragma unroll
  for (int p = 0; p < 25; ++p) {
    float v = al * (keff[p] * 0.125f);
    if (p == 12) v -= THETA * sumw;             // fold 1x1 branch into center
    size_t idx = ((((size_t)p * 4 + kc) * 2 + oh) * 64 + lane) * 8 + (ci & 7);
    apack[idx] = f2bf(v);
  }
}

// ---------------- kernel 2: FUSED conv, channel-phased pipeline -----------
// R14 geometry/compute/epilogue verbatim. NEW: stage split into 4 disjoint
// channel-group phases (ch-group p = logical granules 2p,2p+1 = exactly
// what kc=p iters read). Phase p: issue stage loads (ch p), compute the 5
// dx-iters of kc=p-1 (hides HBM latency), ds_write ch p mid-phase, one
// lgkm-only barrier. First barrier waits on 1/4 of the stage; 3/4 hides
// under MFMA. cvt via v_cvt_pk_bf16_f32 (1 instr / 2 vals, RNE).
#define ROWB 9216   // 72 cols * 128 B

#define MM(A, B, C) __builtin_amdgcn_mfma_f32_32x32x16_bf16((A), __builtin_bit_cast(bf16x8, (B)), (C), 0, 0, 0)

#define PK2(A_, B_) ({ u32 r_;                                              \
    asm("v_cvt_pk_bf16_f32 %0, %1, %2" : "=v"(r_) : "v"(A_), "v"(B_));      \
    r_; })

#define LDBR(S, DX, KC) do {                                                \
    const char* pb_ = pcol + (DX) * 128;                                    \
    int gx_ = ((((KC) * 2 + lhi) ^ ((l31 + (DX) + 2) & 7)) << 4);           \
    br##S##0 = *(const u32x4*)(pb_ + 0 * ROWB + gx_);                       \
    br##S##1 = *(const u32x4*)(pb_ + 1 * ROWB + gx_);                       \
    br##S##2 = *(const u32x4*)(pb_ + 2 * ROWB + gx_);                       \
    br##S##3 = *(const u32x4*)(pb_ + 3 * ROWB + gx_);                       \
    br##S##4 = *(const u32x4*)(pb_ + 4 * ROWB + gx_);                       \
    br##S##5 = *(const u32x4*)(pb_ + 5 * ROWB + gx_);                       \
    br##S##6 = *(const u32x4*)(pb_ + 6 * ROWB + gx_);                       \
    br##S##7 = *(const u32x4*)(pb_ + 7 * ROWB + gx_);                       \
  } while (0)

#define LDAF(S, DX, KC) do {                                                \
    af##S##0 = apb[(size_t)((0 * 5 + (DX)) * 512 + (KC) * 128)];            \
    af##S##1 = apb[(size_t)((1 * 5 + (DX)) * 512 + (KC) * 128)];            \
    af##S##2 = apb[(size_t)((2 * 5 + (DX)) * 512 + (KC) * 128)];            \
    af##S##3 = apb[(size_t)((3 * 5 + (DX)) * 512 + (KC) * 128)];            \
    af##S##4 = apb[(size_t)((4 * 5 + (DX)) * 512 + (KC) * 128)];            \
  } while (0)

#define BURST(S) do {                                                       \
    bf16x8 A_;                                                              \
    A_ = __builtin_bit_cast(bf16x8, af##S##0);                              \
    a0 = MM(A_, br##S##0, a0); a1 = MM(A_, br##S##1, a1);                   \
    a2 = MM(A_, br##S##2, a2); a3 = MM(A_, br##S##3, a3);                   \
    A_ = __builtin_bit_cast(bf16x8, af##S##1);                              \
    a0 = MM(A_, br##S##1, a0); a1 = MM(A_, br##S##2, a1);                   \
    a2 = MM(A_, br##S##3, a2); a3 = MM(A_, br##S##4, a3);                   \
    A_ = __builtin_bit_cast(bf16x8, af##S##2);                              \
    a0 = MM(A_, br##S##2, a0); a1 = MM(A_, br##S##3, a1);                   \
    a2 = MM(A_, br##S##4, a2); a3 = MM(A_, br##S##5, a3);                   \
    A_ = __builtin_bit_cast(bf16x8, af##S##3);                              \
    a0 = MM(A_, br##S##3, a0); a1 = MM(A_, br##S##4, a1);                   \
    a2 = MM(A_, br##S##5, a2); a3 = MM(A_, br##S##6, a3);                   \
    A_ = __builtin_bit_cast(bf16x8, af##S##4);                              \
    a0 = MM(A_, br##S##4, a0); a1 = MM(A_, br##S##5, a1);                   \
    a2 = MM(A_, br##S##6, a2); a3 = MM(A_, br##S##7, a3);                   \
  } while (0)

#define SGB __builtin_amdgcn_sched_group_barrier
#define SCHED_FULL() do {                                                   \
    SGB(0x020, 5, 0);                                                       \
    SGB(0x100, 2, 0); SGB(0x008, 5, 0);                                     \
    SGB(0x100, 2, 0); SGB(0x008, 5, 0);                                     \
    SGB(0x100, 2, 0); SGB(0x008, 5, 0);                                     \
    SGB(0x100, 2, 0); SGB(0x008, 5, 0);                                     \
  } while (0)

#define ITER(CUR, NXT, DXN, KCN) do {                                       \
    LDBR(NXT, DXN, KCN); LDAF(NXT, DXN, KCN); BURST(CUR); SCHED_FULL();     \
  } while (0)

#define TBAR() do {                                                         \
    asm volatile("s_waitcnt lgkmcnt(0)" ::: "memory");                      \
    __builtin_amdgcn_sched_barrier(0);                                      \
    __builtin_amdgcn_s_barrier();                                           \
    __builtin_amdgcn_sched_barrier(0);                                      \
  } while (0)

// stage loads for ch-group P (granule 2P+gp): thread = (rr, quad, gp)
#define SLOADP(P) do {                                                      \
    if (rowok) {                                                            \
      const float* pm_ = xrow + (size_t)(16 * (P) + 8 * gp) * 16384 + pxm;  \
      sm0 = *(const f32x4*)(pm_);              sm1 = *(const f32x4*)(pm_ + 16384);      \
      sm2 = *(const f32x4*)(pm_ + 2 * 16384);  sm3 = *(const f32x4*)(pm_ + 3 * 16384);  \
      sm4 = *(const f32x4*)(pm_ + 4 * 16384);  sm5 = *(const f32x4*)(pm_ + 5 * 16384);  \
      sm6 = *(const f32x4*)(pm_ + 6 * 16384);  sm7 = *(const f32x4*)(pm_ + 7 * 16384);  \
    } else {                                                                \
      sm0 = 0; sm1 = 0; sm2 = 0; sm3 = 0; sm4 = 0; sm5 = 0; sm6 = 0; sm7 = 0; \
    }                                                                       \
    if (hdut) {                                                             \
      if (hok) {                                                            \
        const float* ph_ = xn + (size_t)hsy * 128                           \
                           + (size_t)(16 * (P) + 8 * hgp) * 16384 + hpx;    \
        sh0 = *(const f32x2*)(ph_);              sh1 = *(const f32x2*)(ph_ + 16384);     \
        sh2 = *(const f32x2*)(ph_ + 2 * 16384);  sh3 = *(const f32x2*)(ph_ + 3 * 16384); \
        sh4 = *(const f32x2*)(ph_ + 4 * 16384);  sh5 = *(const f32x2*)(ph_ + 5 * 16384); \
        sh6 = *(const f32x2*)(ph_ + 6 * 16384);  sh7 = *(const f32x2*)(ph_ + 7 * 16384); \
      } else {                                                              \
        sh0 = 0; sh1 = 0; sh2 = 0; sh3 = 0; sh4 = 0; sh5 = 0; sh6 = 0; sh7 = 0; \
      }                                                                     \
    }                                                                       \
  } while (0)

// stage writes for ch-group P (4 main cols + 2 halo cols), bank-swizzled
#define SWRITEP(P) do {                                                     \
    int g_ = 2 * (P) + gp;                                                  \
    u32x4 w_;                                                               \
    w_[0] = PK2(sm0.x, sm1.x); w_[1] = PK2(sm2.x, sm3.x);                   \
    w_[2] = PK2(sm4.x, sm5.x); w_[3] = PK2(sm6.x, sm7.x);                   \
    *(u32x4*)(rowbase + cbm * 128 + ((g_ ^ (cbm & 7)) << 4)) = w_;          \
    w_[0] = PK2(sm0.y, sm1.y); w_[1] = PK2(sm2.y, sm3.y);                   \
    w_[2] = PK2(sm4.y, sm5.y); w_[3] = PK2(sm6.y, sm7.y);                   \
    *(u32x4*)(rowbase + (cbm + 1) * 128 + ((g_ ^ ((cbm + 1) & 7)) << 4)) = w_; \
    w_[0] = PK2(sm0.z, sm1.z); w_[1] = PK2(sm2.z, sm3.z);                   \
    w_[2] = PK2(sm4.z, sm5.z); w_[3] = PK2(sm6.z, sm7.z);                   \
    *(u32x4*)(rowbase + (cbm + 2) * 128 + ((g_ ^ ((cbm + 2) & 7)) << 4)) = w_; \
    w_[0] = PK2(sm0.w, sm1.w); w_[1] = PK2(sm2.w, sm3.w);                   \
    w_[2] = PK2(sm4.w, sm5.w); w_[3] = PK2(sm6.w, sm7.w);                   \
    *(u32x4*)(rowbase + (cbm + 3) * 128 + ((g_ ^ ((cbm + 3) & 7)) << 4)) = w_; \
    if (hdut) {                                                             \
      int hg_ = 2 * (P) + hgp;                                              \
      u32x4 u_;                                                             \
      u_[0] = PK2(sh0.x, sh1.x); u_[1] = PK2(sh2.x, sh3.x);                 \
      u_[2] = PK2(sh4.x, sh5.x); u_[3] = PK2(sh6.x, sh7.x);                 \
      *(u32x4*)(hrowbase + hc * 128 + ((hg_ ^ (hc & 7)) << 4)) = u_;        \
      u_[0] = PK2(sh0.y, sh1.y); u_[1] = PK2(sh2.y, sh3.y);                 \
      u_[2] = PK2(sh4.y, sh5.y); u_[3] = PK2(sh6.y, sh7.y);                 \
      *(u32x4*)(hrowbase + (hc + 1) * 128 + ((hg_ ^ ((hc + 1) & 7)) << 4)) = u_; \
    }                                                                       \
  } while (0)

// one pipelined phase: stage ch-group SP while computing kc=CP
#define CPHASE(SP, CP) do {                                                 \
    SLOADP(SP);                                                             \
    LDBR(A, 0, CP); LDAF(A, 0, CP);                                         \
    ITER(A, B, 1, CP);                                                      \
    ITER(B, A, 2, CP);                                                      \
    SWRITEP(SP);                                                            \
    ITER(A, B, 3, CP);                                                      \
    ITER(B, A, 4, CP);                                                      \
    BURST(A);                                                               \
    TBAR();                                                                 \
  } while (0)

__global__ __launch_bounds__(256, 2) void k_conv(const float* __restrict__ x,
                                                 const u32x4* __restrict__ apv,
                                                 float* __restrict__ out) {
  __shared__ char tile[8 * ROWB];             // 73728 B -> 2 blocks/CU
  int bid = blockIdx.x;
  int lg = (bid & 7) * 256 + (bid >> 3);      // XCD swizzle (2048%8==0)
  int ph = lg & 1, yt = (lg >> 1) & 31, n = lg >> 6;
  int y0 = yt * 4, px0 = ph * 64;
  int tid = threadIdx.x;
  int l = tid & 63;

  // ---- stage thread mapping: (row rr, quad qq, granule parity gp) ----
  const float* xn = x + (size_t)n * (64 * 16384);
  int rr = tid >> 5, qq = (tid >> 1) & 15, gp = tid & 1;
  int sy = y0 + rr - 2;
  bool rowok = (unsigned)sy < 128u;
  const float* xrow = xn + (size_t)(rowok ? sy : 0) * 128;
  int pxm = px0 + 4 * qq;
  int cbm = 4 + 4 * qq;
  char* rowbase = tile + rr * ROWB;
  bool hdut = tid < 32;                       // halo: (hrr, side, hgp)
  int hrr = tid >> 2, hside = (tid >> 1) & 1, hgp = tid & 1;
  int hpx = hside ? px0 + 64 : px0 - 2;
  int hc = hside ? 68 : 2;
  int hsy = y0 + hrr - 2;
  bool hok = ((unsigned)hpx < 127u) && ((unsigned)hsy < 128u);
  if (!hok) hsy = 0; if (hpx < 0) hpx = 0;
  char* hrowbase = tile + hrr * ROWB;

  // ---- compute mapping (R14 verbatim) ----
  int wv = tid >> 6;
  int oh = wv >> 1, q32 = wv & 1;
  int l31 = l & 31, lhi = l >> 5;
  const u32x4* apb = apv + (size_t)(oh * 64 + l);
  const char* pcol = tile + (q32 * 32 + l31 + 2) * 128;

  f32x4 sm0, sm1, sm2, sm3, sm4, sm5, sm6, sm7;
  f32x2 sh0, sh1, sh2, sh3, sh4, sh5, sh6, sh7;
  u32x4 brA0, brA1, brA2, brA3, brA4, brA5, brA6, brA7;
  u32x4 brB0, brB1, brB2, brB3, brB4, brB5, brB6, brB7;
  u32x4 afA0, afA1, afA2, afA3, afA4;
  u32x4 afB0, afB1, afB2, afB3, afB4;
  f32x16 a0 = 0, a1 = 0, a2 = 0, a3 = 0;

  // phase 0: stage ch-group 0 only
  SLOADP(0);
  SWRITEP(0);
  TBAR();
  // phases 1..3: stage ch-group p, compute kc=p-1
  CPHASE(1, 0);
  CPHASE(2, 1);
  CPHASE(3, 2);
  // phase 4: compute kc=3 (no stage, no barrier)
  LDBR(A, 0, 3); LDAF(A, 0, 3);
  ITER(A, B, 1, 3);
  ITER(B, A, 2, 3);
  ITER(A, B, 3, 3);
  ITER(B, A, 4, 3);
  BURST(A);

  // ---- epilogue: C/D layout col=lane&31, row=(rg&3)+8*(rg>>2)+4*(lane>>5)
  float* ob = out + ((size_t)(n * 64 + oh * 32) * 128 + y0) * 128
              + px0 + q32 * 32 + l31;
#pragma unroll
  for (int rg = 0; rg < 16; ++rg) {
    int orow = (rg & 3) + 8 * (rg >> 2) + 4 * lhi;
    float* obr = ob + (size_t)orow * 16384;
    obr[0]   = a0[rg];
    obr[128] = a1[rg];
    obr[256] = a2[rg];
    obr[384] = a3[rg];
  }
}

extern "C" void kernel_launch(void* const* d_in, const int* in_sizes, int n_in,
                              void* d_out, int out_size, void* d_ws, size_t ws_size,
                              hipStream_t stream) {
  const float* x     = (const float*)d_in[0];   // (32,64,128,128) fp32
  const float* wgt   = (const float*)d_in[1];   // (64,64,5,5) fp32
  const float* alpha = (const float*)d_in[2];   // (1,) fp32
  float* out = (float*)d_out;

  u16* apack = (u16*)d_ws;                      // 204800 B

  k_prep<<<16,   256, 0, stream>>>(wgt, alpha, apack);
  k_conv<<<2048, 256, 0, stream>>>(x, (const u32x4*)apack, out);
}